// Round 7
// baseline (115.364 us; speedup 1.0000x reference)
//
#include <hip/hip_runtime.h>

// Problem shape: E=524288, IN=256, OUT=256, T=16
//   y[t] = x_j[t] @ W[t]       (tiny compute: W is 4 MB total)
//   out[e] = y[edge_types[e]]  (memory-bound gather: 512 MB fp32 writes)
//
// R6 post-mortem: per-wave long spans REGRESSED (4.8 TB/s). The fill kernel
// (6.7 TB/s) is a grid-stride WINDOW SWEEP: whole chip writes one ~8 MB
// contiguous moving window -> max DRAM row-buffer locality. R7: chunked
// sweep (4 KB/wave/step, 32 MB chip window, 16 sweeps), et fully prefetched
// per wave into LDS, 2048 blocks (8/CU) for latency hiding, nt stores.

#define RL_IN  256
#define RL_OUT 256
#define RL_T   16

typedef float f32x4 __attribute__((ext_vector_type(4)));

// ---------------------------------------------------------------------------
// Kernel A (fused): y[t][o] = sum_i x[t][i] * W[t][i][o].
// 16 blocks x 1024 threads; thread (c,o) sums 64 i's; LDS reduce over c.
// ---------------------------------------------------------------------------
__global__ __launch_bounds__(1024)
void rl_compute_y(const float* __restrict__ x,
                  const float* __restrict__ W,
                  float* __restrict__ y) {
    const int t = blockIdx.x;            // 0..15
    const int c = threadIdx.x >> 8;      // 0..3
    const int o = threadIdx.x & 255;     // 0..255
    const int i0 = c * 64;

    __shared__ float xs[RL_IN];
    if (threadIdx.x < RL_IN) xs[threadIdx.x] = x[t * RL_IN + threadIdx.x];
    __syncthreads();

    const float* Wt = W + (size_t)t * RL_IN * RL_OUT + (size_t)i0 * RL_OUT;
    float acc = 0.0f;
#pragma unroll 8
    for (int i = 0; i < 64; ++i) {
        acc += xs[i0 + i] * Wt[i * RL_OUT + o];
    }

    __shared__ float part[4][RL_OUT];
    part[c][o] = acc;
    __syncthreads();
    if (c == 0) {
        y[t * RL_OUT + o] = part[0][o] + part[1][o] + part[2][o] + part[3][o];
    }
}

// ---------------------------------------------------------------------------
// Kernel B: gather, chunked window sweep.
// Wave w, step s -> int4 group g = w + s*nW (4 rows = 4 KB contiguous).
// Chip-wide per-step window = nW*4KB = 32 MB, swept E/(4*nW)=16 times.
// Per super-iteration (16 steps) the wave prefetches its 16 et-int4s into
// LDS with one lane-parallel burst; steady state has NO global reads.
// ---------------------------------------------------------------------------
__global__ __launch_bounds__(256)
void rl_gather(const int* __restrict__ et,    // [E]
               const f32x4* __restrict__ y4,  // [T*64]
               f32x4* __restrict__ out4,      // [E*64]
               int E) {
    __shared__ f32x4 ys[RL_T * (RL_OUT / 4)];  // 1024 * 16B = 16 KB
    __shared__ int4  tys[4][16];               // per-wave step types, 1 KB

    for (int i = threadIdx.x; i < RL_T * (RL_OUT / 4); i += blockDim.x)
        ys[i] = y4[i];

    const int lane = threadIdx.x & 63;
    const int w    = threadIdx.x >> 6;          // wave in block
    const int gw   = blockIdx.x * 4 + w;        // global wave id
    const int nW   = gridDim.x * 4;             // total waves (8192)
    const int G    = E >> 2;                    // int4 groups (131072)
    const int4* et4 = (const int4*)et;

    __syncthreads();  // ys ready

    for (int j0 = 0; j0 * nW + gw < G; j0 += 16) {  // super-iteration
        // prefetch the next 16 steps' types for this wave (lanes 0..15)
        if (lane < 16) {
            const int g = gw + (j0 + lane) * nW;
            tys[w][lane] = (g < G) ? et4[g] : make_int4(0, 0, 0, 0);
        }
        // same-wave LDS write->read: compiler inserts lgkmcnt wait
#pragma unroll
        for (int s = 0; s < 16; ++s) {
            const int g = gw + (j0 + s) * nW;
            if (g >= G) break;
            const int4 tv = tys[w][s];           // uniform LDS broadcast
            const size_t r0 = (size_t)g * 4;
            f32x4 v0 = ys[tv.x * 64 + lane];
            f32x4 v1 = ys[tv.y * 64 + lane];
            f32x4 v2 = ys[tv.z * 64 + lane];
            f32x4 v3 = ys[tv.w * 64 + lane];
            __builtin_nontemporal_store(v0, &out4[(r0 + 0) * 64 + lane]);
            __builtin_nontemporal_store(v1, &out4[(r0 + 1) * 64 + lane]);
            __builtin_nontemporal_store(v2, &out4[(r0 + 2) * 64 + lane]);
            __builtin_nontemporal_store(v3, &out4[(r0 + 3) * 64 + lane]);
        }
    }
}

extern "C" void kernel_launch(void* const* d_in, const int* in_sizes, int n_in,
                              void* d_out, int out_size, void* d_ws, size_t ws_size,
                              hipStream_t stream) {
    const float* x_j  = (const float*)d_in[0];   // [E, IN] (first T rows used)
    const float* W    = (const float*)d_in[1];   // [T, IN, OUT]
    const int*   et   = (const int*)d_in[2];     // [E]
    float*       out  = (float*)d_out;           // [E, OUT]

    const int E = in_sizes[2];                   // 524288

    float* y = (float*)d_ws;                     // [T, OUT] = 16 KB scratch

    rl_compute_y<<<RL_T, 1024, 0, stream>>>(x_j, W, y);

    // 2048 blocks x 4 waves = 8192 waves (8 blocks/CU, all resident).
    rl_gather<<<2048, 256, 0, stream>>>(et, (const f32x4*)y,
                                        (f32x4*)out, E);
}

// Round 8
// 108.253 us; speedup vs baseline: 1.0657x; 1.0657x over previous
//
#include <hip/hip_runtime.h>

// Problem shape: E=524288, IN=256, OUT=256, T=16
//   y[t] = x_j[t] @ W[t]       (tiny compute: W is 4 MB total)
//   out[e] = y[edge_types[e]]  (memory-bound gather: 512 MB fp32 writes)
//
// R7 post-mortem: window-sweep theory falsified (R7 < R4 < R5). Winner so
// far: R5 = 64-row (64 KB) private span per wave, et burst to LDS, 8192
// waves. The 6.7 TB/s fill uses PLAIN stores; theory: L2 write-allocate
// acts as a reorder/combine buffer for the 8192 interleaved streams, and
// nt bypasses it (issue-order traffic -> DRAM row thrash).
// R8 = R5 exactly, single change: plain stores instead of nontemporal.

#define RL_IN  256
#define RL_OUT 256
#define RL_T   16

typedef float f32x4 __attribute__((ext_vector_type(4)));

// ---------------------------------------------------------------------------
// Kernel A (fused): y[t][o] = sum_i x[t][i] * W[t][i][o].
// 16 blocks x 1024 threads; thread (c,o) sums 64 i's; LDS reduce over c.
// ---------------------------------------------------------------------------
__global__ __launch_bounds__(1024)
void rl_compute_y(const float* __restrict__ x,
                  const float* __restrict__ W,
                  float* __restrict__ y) {
    const int t = blockIdx.x;            // 0..15
    const int c = threadIdx.x >> 8;      // 0..3
    const int o = threadIdx.x & 255;     // 0..255
    const int i0 = c * 64;

    __shared__ float xs[RL_IN];
    if (threadIdx.x < RL_IN) xs[threadIdx.x] = x[t * RL_IN + threadIdx.x];
    __syncthreads();

    const float* Wt = W + (size_t)t * RL_IN * RL_OUT + (size_t)i0 * RL_OUT;
    float acc = 0.0f;
#pragma unroll 8
    for (int i = 0; i < 64; ++i) {
        acc += xs[i0 + i] * Wt[i * RL_OUT + o];
    }

    __shared__ float part[4][RL_OUT];
    part[c][o] = acc;
    __syncthreads();
    if (c == 0) {
        y[t * RL_OUT + o] = part[0][o] + part[1][o] + part[2][o] + part[3][o];
    }
}

// ---------------------------------------------------------------------------
// Kernel B: gather (R5 structure). One wave owns a contiguous 64-row (64 KB)
// span. Prologue: one coalesced 256 B et burst -> LDS. Steady state: 64
// independent 1 KB PLAIN stores; type lookup = wave-uniform LDS broadcast.
// ---------------------------------------------------------------------------
__global__ __launch_bounds__(256)
void rl_gather(const int* __restrict__ et,    // [E]
               const f32x4* __restrict__ y4,  // [T*64]
               f32x4* __restrict__ out4,      // [E*64]
               int E) {
    __shared__ f32x4 ys[RL_T * (RL_OUT / 4)];  // 1024 * 16B = 16 KB
    __shared__ int tys[256];                   // per-thread type slot

    for (int i = threadIdx.x; i < RL_T * (RL_OUT / 4); i += blockDim.x)
        ys[i] = y4[i];
    __syncthreads();

    const int lane       = threadIdx.x & 63;
    const int waveBase   = threadIdx.x & ~63;   // LDS base for this wave's types
    const int wave       = blockIdx.x * (blockDim.x >> 6) + (threadIdx.x >> 6);
    const int totalWaves = gridDim.x * (blockDim.x >> 6);

    for (int base = wave * 64; base < E; base += totalWaves * 64) {
        // one coalesced 256 B read per wave; parked in LDS (same-wave use,
        // no barrier needed -- compiler inserts lgkmcnt waits)
        tys[waveBase + lane] = et[base + lane];

        if (base + 64 <= E) {
#pragma unroll 8
            for (int r = 0; r < 64; ++r) {
                const int t = tys[waveBase + r];        // uniform broadcast
                out4[(size_t)(base + r) * 64 + lane] = ys[t * 64 + lane];
            }
        } else {
            for (int r = 0; base + r < E; ++r) {
                const int t = tys[waveBase + r];
                out4[(size_t)(base + r) * 64 + lane] = ys[t * 64 + lane];
            }
        }
    }
}

extern "C" void kernel_launch(void* const* d_in, const int* in_sizes, int n_in,
                              void* d_out, int out_size, void* d_ws, size_t ws_size,
                              hipStream_t stream) {
    const float* x_j  = (const float*)d_in[0];   // [E, IN] (first T rows used)
    const float* W    = (const float*)d_in[1];   // [T, IN, OUT]
    const int*   et   = (const int*)d_in[2];     // [E]
    float*       out  = (float*)d_out;           // [E, OUT]

    const int E = in_sizes[2];                   // 524288

    float* y = (float*)d_ws;                     // [T, OUT] = 16 KB scratch

    rl_compute_y<<<RL_T, 1024, 0, stream>>>(x_j, W, y);

    rl_gather<<<2048, 256, 0, stream>>>(et, (const f32x4*)y,
                                        (f32x4*)out, E);
}

// Round 9
// 107.718 us; speedup vs baseline: 1.0710x; 1.0050x over previous
//
#include <hip/hip_runtime.h>

// Problem shape: E=524288, IN=256, OUT=256, T=16
//   y[t] = x_j[t] @ W[t]       (tiny compute: W is 4 MB total)
//   out[e] = y[edge_types[e]]  (memory-bound gather: 512 MB fp32 writes)
//
// R8 post-mortem: plain stores regressed vs nt (108.3 vs 103.4) -> keep nt.
// Remaining suspect for the 5.3 vs 6.7 TB/s gap: every store gated on a
// 2-hop LDS chain (type read -> ys b128 read -> lgkmcnt -> store).
// R9: ZERO memory ops in the store loop. Per wave: 64 types in a register
// (lane r = type of row r), 16 y-fragments preloaded into registers
// (static index via unrolled t-loop), then per type: ballot -> uniform
// while(popbit) -> v_add + nt store. Byte-identical loop body to the fill.

#define RL_IN  256
#define RL_OUT 256
#define RL_T   16

typedef float f32x4 __attribute__((ext_vector_type(4)));

// ---------------------------------------------------------------------------
// Kernel A (fused): y[t][o] = sum_i x[t][i] * W[t][i][o].
// 16 blocks x 1024 threads; thread (c,o) sums 64 i's; LDS reduce over c.
// ---------------------------------------------------------------------------
__global__ __launch_bounds__(1024)
void rl_compute_y(const float* __restrict__ x,
                  const float* __restrict__ W,
                  float* __restrict__ y) {
    const int t = blockIdx.x;            // 0..15
    const int c = threadIdx.x >> 8;      // 0..3
    const int o = threadIdx.x & 255;     // 0..255
    const int i0 = c * 64;

    __shared__ float xs[RL_IN];
    if (threadIdx.x < RL_IN) xs[threadIdx.x] = x[t * RL_IN + threadIdx.x];
    __syncthreads();

    const float* Wt = W + (size_t)t * RL_IN * RL_OUT + (size_t)i0 * RL_OUT;
    float acc = 0.0f;
#pragma unroll 8
    for (int i = 0; i < 64; ++i) {
        acc += xs[i0 + i] * Wt[i * RL_OUT + o];
    }

    __shared__ float part[4][RL_OUT];
    part[c][o] = acc;
    __syncthreads();
    if (c == 0) {
        y[t * RL_OUT + o] = part[0][o] + part[1][o] + part[2][o] + part[3][o];
    }
}

// ---------------------------------------------------------------------------
// Kernel B: gather, register-resident. One wave owns a contiguous 64-row
// (64 KB) span. Prologue: et[base+lane] -> VGPR (lane r = type of row r);
// y fragments for all 16 types -> 16 f32x4 registers (statically indexed).
// Store loop: per type t, ballot(tv==t) -> uniform bit-pop loop issuing
// pure {v_add, global_store_dwordx4 nt}. No LDS/loads in the loop.
// ---------------------------------------------------------------------------
__global__ __launch_bounds__(256)
void rl_gather(const int* __restrict__ et,    // [E]
               const f32x4* __restrict__ y4,  // [T*64]
               f32x4* __restrict__ out4,      // [E*64]
               int E) {
    const int lane       = threadIdx.x & 63;
    const int wave       = blockIdx.x * (blockDim.x >> 6) + (threadIdx.x >> 6);
    const int totalWaves = gridDim.x * (blockDim.x >> 6);

    // Preload this lane's fragment of every type's y row: y16[t] = y4[t*64+lane].
    // Coalesced b128 loads; y is 16 KB, L2/L3-hot after first touches.
    f32x4 y16[RL_T];
#pragma unroll
    for (int t = 0; t < RL_T; ++t)
        y16[t] = y4[t * 64 + lane];

    for (long base = (long)wave * 64; base + 64 <= E; base += (long)totalWaves * 64) {
        const int tv = et[base + lane];          // lane r holds type of row r
        f32x4* __restrict__ dst = out4 + (size_t)base * 64;  // wave-uniform

#pragma unroll
        for (int t = 0; t < RL_T; ++t) {
            unsigned long long m = __ballot(tv == t);   // rows of type t
            const f32x4 v = y16[t];                     // static index
            while (m) {
                const int r = __builtin_ctzll(m);
                m &= m - 1;
                __builtin_nontemporal_store(v, &dst[r * 64 + lane]);
            }
        }
    }

    // Generic tail (E not multiple of 64) — not taken at E=524288.
    const long tail = (long)(E & ~63LL);
    for (long row = tail + wave; row < E; row += totalWaves) {
        const int t = et[row];
        f32x4 v;
#pragma unroll
        for (int tt = 0; tt < RL_T; ++tt)
            if (tt == t) v = y16[tt];
        __builtin_nontemporal_store(v, &out4[(size_t)row * 64 + lane]);
    }
}

extern "C" void kernel_launch(void* const* d_in, const int* in_sizes, int n_in,
                              void* d_out, int out_size, void* d_ws, size_t ws_size,
                              hipStream_t stream) {
    const float* x_j  = (const float*)d_in[0];   // [E, IN] (first T rows used)
    const float* W    = (const float*)d_in[1];   // [T, IN, OUT]
    const int*   et   = (const int*)d_in[2];     // [E]
    float*       out  = (float*)d_out;           // [E, OUT]

    const int E = in_sizes[2];                   // 524288

    float* y = (float*)d_ws;                     // [T, OUT] = 16 KB scratch

    rl_compute_y<<<RL_T, 1024, 0, stream>>>(x_j, W, y);

    // 2048 blocks x 4 waves = 8192 waves; one 64-row span each at E=524288.
    rl_gather<<<2048, 256, 0, stream>>>(et, (const f32x4*)y,
                                        (f32x4*)out, E);
}

// Round 10
// 102.479 us; speedup vs baseline: 1.1257x; 1.0511x over previous
//
#include <hip/hip_runtime.h>

// Problem shape: E=524288, IN=256, OUT=256, T=16
//   y[t] = x_j[t] @ W[t]       (tiny compute: W is 4 MB total)
//   out[e] = y[edge_types[e]]  (memory-bound gather: 512 MB fp32 writes)
//
// R9 post-mortem: register-resident stores != faster -> issue-side fully
// exonerated (granule, nt, dependency, window all tested). Last axis:
// stream count. Fills sustain 6.7 TB/s at ~3.4 waves/CU (~870 streams);
// we run 8192 streams. R10 = champion R5, grid 2048 -> 1024 blocks
// (16 waves/CU, 2 spans/wave): halve concurrent streams, keep latency
// hiding (4 waves/SIMD) and the proven 64-row-span + nt structure.

#define RL_IN  256
#define RL_OUT 256
#define RL_T   16

typedef float f32x4 __attribute__((ext_vector_type(4)));

// ---------------------------------------------------------------------------
// Kernel A (fused): y[t][o] = sum_i x[t][i] * W[t][i][o].
// 16 blocks x 1024 threads; thread (c,o) sums 64 i's; LDS reduce over c.
// ---------------------------------------------------------------------------
__global__ __launch_bounds__(1024)
void rl_compute_y(const float* __restrict__ x,
                  const float* __restrict__ W,
                  float* __restrict__ y) {
    const int t = blockIdx.x;            // 0..15
    const int c = threadIdx.x >> 8;      // 0..3
    const int o = threadIdx.x & 255;     // 0..255
    const int i0 = c * 64;

    __shared__ float xs[RL_IN];
    if (threadIdx.x < RL_IN) xs[threadIdx.x] = x[t * RL_IN + threadIdx.x];
    __syncthreads();

    const float* Wt = W + (size_t)t * RL_IN * RL_OUT + (size_t)i0 * RL_OUT;
    float acc = 0.0f;
#pragma unroll 8
    for (int i = 0; i < 64; ++i) {
        acc += xs[i0 + i] * Wt[i * RL_OUT + o];
    }

    __shared__ float part[4][RL_OUT];
    part[c][o] = acc;
    __syncthreads();
    if (c == 0) {
        y[t * RL_OUT + o] = part[0][o] + part[1][o] + part[2][o] + part[3][o];
    }
}

// ---------------------------------------------------------------------------
// Kernel B: gather (R5 structure). One wave owns a contiguous 64-row (64 KB)
// span per loop iteration. Prologue: one coalesced 256 B et burst -> LDS.
// Steady state: 64 independent 1 KB nt stores; type lookup = wave-uniform
// LDS broadcast.
// ---------------------------------------------------------------------------
__global__ __launch_bounds__(256)
void rl_gather(const int* __restrict__ et,    // [E]
               const f32x4* __restrict__ y4,  // [T*64]
               f32x4* __restrict__ out4,      // [E*64]
               int E) {
    __shared__ f32x4 ys[RL_T * (RL_OUT / 4)];  // 1024 * 16B = 16 KB
    __shared__ int tys[256];                   // per-thread type slot

    for (int i = threadIdx.x; i < RL_T * (RL_OUT / 4); i += blockDim.x)
        ys[i] = y4[i];
    __syncthreads();

    const int lane       = threadIdx.x & 63;
    const int waveBase   = threadIdx.x & ~63;   // LDS base for this wave's types
    const int wave       = blockIdx.x * (blockDim.x >> 6) + (threadIdx.x >> 6);
    const int totalWaves = gridDim.x * (blockDim.x >> 6);

    for (long base = (long)wave * 64; base < E; base += (long)totalWaves * 64) {
        // one coalesced 256 B read per wave; parked in LDS (same-wave use,
        // no barrier needed -- compiler inserts lgkmcnt waits)
        tys[waveBase + lane] = et[base + lane];

        if (base + 64 <= E) {
#pragma unroll 8
            for (int r = 0; r < 64; ++r) {
                const int t = tys[waveBase + r];        // uniform broadcast
                __builtin_nontemporal_store(
                    ys[t * 64 + lane], &out4[(size_t)(base + r) * 64 + lane]);
            }
        } else {
            for (int r = 0; base + r < E; ++r) {
                const int t = tys[waveBase + r];
                __builtin_nontemporal_store(
                    ys[t * 64 + lane], &out4[(size_t)(base + r) * 64 + lane]);
            }
        }
    }
}

extern "C" void kernel_launch(void* const* d_in, const int* in_sizes, int n_in,
                              void* d_out, int out_size, void* d_ws, size_t ws_size,
                              hipStream_t stream) {
    const float* x_j  = (const float*)d_in[0];   // [E, IN] (first T rows used)
    const float* W    = (const float*)d_in[1];   // [T, IN, OUT]
    const int*   et   = (const int*)d_in[2];     // [E]
    float*       out  = (float*)d_out;           // [E, OUT]

    const int E = in_sizes[2];                   // 524288

    float* y = (float*)d_ws;                     // [T, OUT] = 16 KB scratch

    rl_compute_y<<<RL_T, 1024, 0, stream>>>(x_j, W, y);

    // 1024 blocks x 4 waves = 4096 waves (16 waves/CU): halve the number of
    // concurrent write streams vs R5; each wave covers 2 spans.
    rl_gather<<<1024, 256, 0, stream>>>(et, (const f32x4*)y,
                                        (f32x4*)out, E);
}